// Round 2
// baseline (217.086 us; speedup 1.0000x reference)
//
#include <hip/hip_runtime.h>

#define NVOX 2097152u          // 128^3 spatial elements per (b,c)
#define NCHUNK_PER_B 524288u   // NVOX / 4
#define NBINS 15
#define NSEG 240               // B*C*NBINS = 4*4*15

// ---------------- kernel A: zero the global accumulators ----------------
__global__ __launch_bounds__(256)
void ace_zero(unsigned* __restrict__ ws) {
    int i = blockIdx.x * 256 + threadIdx.x;
    if (i < 3 * NSEG) ws[i] = 0u;
}

// ---------------- kernel B: fused softmax + histogram ----------------
// ws layout: g_cnt[240] (u32), g_cntt[240] (u32), g_sump[240] (f32)
__global__ __launch_bounds__(256)
void ace_hist(const float* __restrict__ logits,
              const int*   __restrict__ labels,     // int32 on device (harness contract)
              unsigned* __restrict__ g_cnt,
              unsigned* __restrict__ g_cntt,
              float*    __restrict__ g_sump)
{
    // per-wave replicated histograms: packed (cnt | cnt_t<<16) + sum_p
    __shared__ unsigned s_pk[4 * NSEG];
    __shared__ float    s_sp[4 * NSEG];

    const int tid  = threadIdx.x;
    const int wave = tid >> 6;
    unsigned* pk = s_pk + wave * NSEG;
    float*    sp = s_sp + wave * NSEG;

    for (int i = tid; i < 4 * NSEG; i += 256) { s_pk[i] = 0u; s_sp[i] = 0.0f; }
    __syncthreads();

    const float step  = (1.0f + 1.1920929e-7f) / 15.0f;   // boundary spacing
    const float scale = 15.0f / (1.0f + 1.1920929e-7f);   // 1/step

    const unsigned T = gridDim.x * blockDim.x;
    const unsigned nchunks = 4u * NCHUNK_PER_B;           // B * NVOX / 4

    for (unsigned ch = blockIdx.x * blockDim.x + tid; ch < nchunks; ch += T) {
        const unsigned b = ch >> 19;                       // ch / NCHUNK_PER_B
        const unsigned s = (ch & (NCHUNK_PER_B - 1u)) << 2;

        // 4 int32 labels (16 B, coalesced)
        const int4 lv4 = *(const int4*)(labels + ((unsigned long long)ch << 2));
        const int lab[4] = { lv4.x, lv4.y, lv4.z, lv4.w };

        // 4 channels x 4 voxels of logits (float4, coalesced)
        const float* base = logits + ((unsigned long long)(b * 4u) * NVOX + s);
        float4 L0 = *(const float4*)(base);
        float4 L1 = *(const float4*)(base + NVOX);
        float4 L2 = *(const float4*)(base + 2u * NVOX);
        float4 L3 = *(const float4*)(base + 3u * NVOX);

        const int rowbase = (int)(b * 4u) * NBINS;

        #pragma unroll
        for (int v = 0; v < 4; ++v) {
            const float x0 = (&L0.x)[v];
            const float x1 = (&L1.x)[v];
            const float x2 = (&L2.x)[v];
            const float x3 = (&L3.x)[v];
            const int   lv = lab[v];

            const float m  = fmaxf(fmaxf(x0, x1), fmaxf(x2, x3));
            const float e0 = __expf(x0 - m);
            const float e1 = __expf(x1 - m);
            const float e2 = __expf(x2 - m);
            const float e3 = __expf(x3 - m);
            const float inv = 1.0f / (e0 + e1 + e2 + e3);
            const float pr[4] = { e0 * inv, e1 * inv, e2 * inv, e3 * inv };

            #pragma unroll
            for (int c = 0; c < 4; ++c) {
                const float pv = pr[c];
                // bin = #{k in 1..15 : k*step < pv}; floor estimate + exact +/-1 fixup
                int bin = (int)(pv * scale);
                bin = bin > 14 ? 14 : bin;
                if (bin < 14 && step * (float)(bin + 1) < pv) ++bin;
                if (bin > 0 && !(step * (float)bin < pv)) --bin;

                const int idx = rowbase + c * NBINS + bin;
                atomicAdd(&pk[idx], (lv == c) ? 0x10001u : 1u);
                atomicAdd(&sp[idx], pv);
            }
        }
    }
    __syncthreads();

    // reduce the 4 wave copies and flush to global accumulators
    for (int i = tid; i < NSEG; i += 256) {
        const unsigned pks = s_pk[i] + s_pk[NSEG + i] + s_pk[2 * NSEG + i] + s_pk[3 * NSEG + i];
        const float    sps = s_sp[i] + s_sp[NSEG + i] + s_sp[2 * NSEG + i] + s_sp[3 * NSEG + i];
        if (pks) {
            atomicAdd(g_cnt + i,  pks & 0xFFFFu);
            atomicAdd(g_cntt + i, pks >> 16);
        }
        if (sps != 0.0f) atomicAdd(g_sump + i, sps);
    }
}

// ---------------- kernel C: final ACE reduction ----------------
__global__ __launch_bounds__(64)
void ace_final(const unsigned* __restrict__ g_cnt,
               const unsigned* __restrict__ g_cntt,
               const float*    __restrict__ g_sump,
               float* __restrict__ out)
{
    const int lane = threadIdx.x;
    float contrib = 0.0f;
    if (lane < 16) {                       // one lane per (b,c)
        float diff_sum = 0.0f;
        int   nvalid   = 0;
        unsigned tot_t = 0u;
        for (int k = 0; k < NBINS; ++k) {
            const int i = lane * NBINS + k;
            const unsigned c  = g_cnt[i];
            const unsigned ct = g_cntt[i];
            const float    sp = g_sump[i];
            tot_t += ct;
            if (c > 0u) {
                const float invc = 1.0f / (float)c;
                diff_sum += fabsf(sp * invc - (float)ct * invc);
                ++nvalid;
            }
        }
        const float ace = diff_sum / (float)(nvalid > 0 ? nvalid : 1);
        contrib = (tot_t > 0u) ? ace : 0.0f;
    }
    #pragma unroll
    for (int off = 32; off > 0; off >>= 1)
        contrib += __shfl_xor(contrib, off, 64);
    if (lane == 0) out[0] = contrib * (1.0f / 16.0f);
}

// ---------------- launch ----------------
extern "C" void kernel_launch(void* const* d_in, const int* in_sizes, int n_in,
                              void* d_out, int out_size, void* d_ws, size_t ws_size,
                              hipStream_t stream) {
    const float* logits = (const float*)d_in[0];
    const int*   labels = (const int*)d_in[1];

    unsigned* g_cnt  = (unsigned*)d_ws;
    unsigned* g_cntt = g_cnt + NSEG;
    float*    g_sump = (float*)(g_cntt + NSEG);
    float*    out    = (float*)d_out;

    ace_zero<<<3, 256, 0, stream>>>((unsigned*)d_ws);
    ace_hist<<<1024, 256, 0, stream>>>(logits, labels, g_cnt, g_cntt, g_sump);
    ace_final<<<1, 64, 0, stream>>>(g_cnt, g_cntt, g_sump, out);
}